// Round 2
// baseline (561.068 us; speedup 1.0000x reference)
//
#include <hip/hip_runtime.h>
#include <cmath>

#ifndef M_PI
#define M_PI 3.14159265358979323846
#endif

static constexpr int CH     = 128;   // channels
static constexpr int NBATCH = 64;    // batch
static constexpr int HWSZ   = 3136;  // 56*56
static constexpr int HW4    = 784;   // HWSZ/4
static constexpr int PARTS  = 16;    // chunks per channel
static constexpr int SLPP   = NBATCH / PARTS;
static constexpr int KTOP   = 10;
static constexpr float EPSV = 1e-5f;

// ---------------------------------------------------------------------------
// k_reduce: per (part, channel) block: sum / min / max (branchless)
// grid = PARTS*CH = 2048 blocks, 256 threads
// ---------------------------------------------------------------------------
__global__ __launch_bounds__(256) void k_reduce(const float* __restrict__ x,
                                                float* __restrict__ sums,
                                                float* __restrict__ mins,
                                                float* __restrict__ maxs) {
  const int bid  = blockIdx.x;
  const int c    = bid & (CH - 1);
  const int part = bid >> 7;
  const int tid  = threadIdx.x;
  const float4* x4 = reinterpret_cast<const float4*>(x);

  float s = 0.f, mn = 3.402823e38f, mx = -3.402823e38f;
  for (int sl = 0; sl < SLPP; ++sl) {
    const size_t base = (size_t)((part * SLPP + sl) * CH + c) * HW4;
    for (int i = tid; i < HW4; i += 256) {
      float4 v = x4[base + i];
      s += (v.x + v.y) + (v.z + v.w);
      mn = fminf(mn, fminf(fminf(v.x, v.y), fminf(v.z, v.w)));
      mx = fmaxf(mx, fmaxf(fmaxf(v.x, v.y), fmaxf(v.z, v.w)));
    }
  }
  for (int off = 32; off; off >>= 1) {
    s  += __shfl_down(s, off);
    mn  = fminf(mn, __shfl_down(mn, off));
    mx  = fmaxf(mx, __shfl_down(mx, off));
  }
  __shared__ float shs[4], shn[4], shx[4];
  const int lane = tid & 63, wid = tid >> 6;
  if (lane == 0) { shs[wid] = s; shn[wid] = mn; shx[wid] = mx; }
  __syncthreads();
  if (tid == 0) {
    sums[bid] = (shs[0] + shs[1]) + (shs[2] + shs[3]);
    mins[bid] = fminf(fminf(shn[0], shn[1]), fminf(shn[2], shn[3]));
    maxs[bid] = fmaxf(fmaxf(shx[0], shx[1]), fmaxf(shx[2], shx[3]));
  }
}

// ---------------------------------------------------------------------------
// k_stats: per channel mean + threshold; zero counters.  <<<1,128>>>
// ---------------------------------------------------------------------------
__global__ __launch_bounds__(128) void k_stats(const float* __restrict__ sums,
                                               const float* __restrict__ mins,
                                               const float* __restrict__ maxs,
                                               float* __restrict__ mu,
                                               float* __restrict__ tau,
                                               unsigned* __restrict__ cnt,
                                               float alpha) {
  const int c = threadIdx.x;
  float s = 0.f, mn = 3.402823e38f, mx = -3.402823e38f;
  #pragma unroll
  for (int p = 0; p < PARTS; ++p) {
    s += sums[p * CH + c];
    mn = fminf(mn, mins[p * CH + c]);
    mx = fmaxf(mx, maxs[p * CH + c]);
  }
  const float m = s * (1.0f / ((float)NBATCH * (float)HWSZ));
  mu[c]  = m;
  tau[c] = alpha * fmaxf(mx - m, m - mn);
  cnt[c] = 0u;
}

// ---------------------------------------------------------------------------
// k_collect: gather dev = |x - mu| >= tau into per-channel candidate buffer
// grid = PARTS*CH, 256 threads
// ---------------------------------------------------------------------------
__global__ __launch_bounds__(256) void k_collect(const float* __restrict__ x,
                                                 const float* __restrict__ mu,
                                                 const float* __restrict__ tau,
                                                 unsigned* __restrict__ cnt,
                                                 float* __restrict__ cand,
                                                 int cap) {
  const int bid  = blockIdx.x;
  const int c    = bid & (CH - 1);
  const int part = bid >> 7;
  const int tid  = threadIdx.x;
  const float m = mu[c], t = tau[c];
  const float4* x4 = reinterpret_cast<const float4*>(x);
  float* cc = cand + (size_t)c * cap;

  for (int sl = 0; sl < SLPP; ++sl) {
    const size_t base = (size_t)((part * SLPP + sl) * CH + c) * HW4;
    for (int i = tid; i < HW4; i += 256) {
      float4 v = x4[base + i];
      float d0 = fabsf(v.x - m), d1 = fabsf(v.y - m);
      float d2 = fabsf(v.z - m), d3 = fabsf(v.w - m);
      if (d0 >= t) { unsigned p = atomicAdd(&cnt[c], 1u); if (p < (unsigned)cap) cc[p] = d0; }
      if (d1 >= t) { unsigned p = atomicAdd(&cnt[c], 1u); if (p < (unsigned)cap) cc[p] = d1; }
      if (d2 >= t) { unsigned p = atomicAdd(&cnt[c], 1u); if (p < (unsigned)cap) cc[p] = d2; }
      if (d3 >= t) { unsigned p = atomicAdd(&cnt[c], 1u); if (p < (unsigned)cap) cc[p] = d3; }
    }
  }
}

// ---------------------------------------------------------------------------
// k_select: exact top-10 of candidates -> (sw, sb).  <<<CH,256, cap*4>>>
// ---------------------------------------------------------------------------
__global__ __launch_bounds__(256) void k_select(const float* __restrict__ cand,
                                                const unsigned* __restrict__ cnt,
                                                const float* __restrict__ mu,
                                                const float* __restrict__ weight,
                                                const float* __restrict__ bias,
                                                float* __restrict__ sw,
                                                float* __restrict__ sb,
                                                int cap, float constv) {
  extern __shared__ float ls[];
  const int c   = blockIdx.x;
  const int tid = threadIdx.x;
  const int n   = (int)min(cnt[c], (unsigned)cap);
  const float* cc = cand + (size_t)c * cap;
  for (int i = tid; i < cap; i += 256) ls[i] = (i < n) ? cc[i] : -1.f;
  __syncthreads();

  __shared__ float swv[4];
  __shared__ int   swi[4];
  __shared__ float tot;
  if (tid == 0) tot = 0.f;
  const int lane = tid & 63, wid = tid >> 6;

  for (int it = 0; it < KTOP; ++it) {
    float best = -2.f; int bi = 0;
    for (int i = tid; i < cap; i += 256) {
      float v = ls[i];
      if (v > best) { best = v; bi = i; }
    }
    for (int off = 32; off; off >>= 1) {
      float ov = __shfl_down(best, off);
      int   oi = __shfl_down(bi, off);
      if (ov > best) { best = ov; bi = oi; }
    }
    if (lane == 0) { swv[wid] = best; swi[wid] = bi; }
    __syncthreads();
    if (tid == 0) {
      float bb = swv[0]; int bbi = swi[0];
      for (int w = 1; w < 4; ++w) if (swv[w] > bb) { bb = swv[w]; bbi = swi[w]; }
      tot += bb;
      ls[bbi] = -2.f;
    }
    __syncthreads();
  }

  if (tid == 0) {
    const float mtk = tot * (1.0f / KTOP) * constv;
    const float inv = 1.f / (mtk + EPSV);
    const float w   = inv * weight[c];
    sw[c] = w;
    sb[c] = bias[c] - mu[c] * w;
  }
}

// ---------------------------------------------------------------------------
// k_affine: out = fma(x, sw[c], sb[c]).  grid = NBATCH*CH, 256 threads
// ---------------------------------------------------------------------------
__global__ __launch_bounds__(256) void k_affine(const float* __restrict__ x,
                                                const float* __restrict__ sw,
                                                const float* __restrict__ sb,
                                                float* __restrict__ out) {
  const int s = blockIdx.x;           // n*CH + c
  const int c = s & (CH - 1);
  const float w = sw[c], b = sb[c];
  const float4* x4 = reinterpret_cast<const float4*>(x) + (size_t)s * HW4;
  float4*       o4 = reinterpret_cast<float4*>(out)     + (size_t)s * HW4;
  for (int i = threadIdx.x; i < HW4; i += 256) {
    float4 v = x4[i];
    float4 r;
    r.x = fmaf(v.x, w, b);
    r.y = fmaf(v.y, w, b);
    r.z = fmaf(v.z, w, b);
    r.w = fmaf(v.w, w, b);
    o4[i] = r;
  }
}

extern "C" void kernel_launch(void* const* d_in, const int* in_sizes, int n_in,
                              void* d_out, int out_size, void* d_ws, size_t ws_size,
                              hipStream_t stream) {
  const float* x      = (const float*)d_in[0];
  const float* weight = (const float*)d_in[1];
  const float* bias   = (const float*)d_in[2];
  float* out = (float*)d_out;
  float* ws  = (float*)d_ws;

  // ws layout (floats)
  float*    sums = ws;                 // 2048
  float*    mins = sums + PARTS * CH;  // 2048
  float*    maxs = mins + PARTS * CH;  // 2048
  float*    mu   = maxs + PARTS * CH;  // 128
  float*    tau  = mu + CH;            // 128
  float*    sw   = tau + CH;           // 128
  float*    sb   = sw + CH;            // 128
  unsigned* cnt  = (unsigned*)(sb + CH); // 128
  float*    cand = (float*)(cnt + CH);
  const size_t FIXED = (size_t)(cand - ws);

  // candidate capacity / threshold ladder based on available scratch
  const size_t avail = ws_size / 4;
  int cap; float alpha;
  if (avail >= FIXED + (size_t)CH * 8192) { cap = 8192; alpha = 0.55f; }
  else if (avail >= FIXED + (size_t)CH * 2048) { cap = 2048; alpha = 0.65f; }
  else { cap = 1024; alpha = 0.70f; }

  const double M = (double)NBATCH * (double)HWSZ;
  const float constv =
      (float)(0.5 * (1.0 + sqrt(M_PI * log(4.0))) / sqrt(2.0 * log(M)));

  k_reduce<<<PARTS * CH, 256, 0, stream>>>(x, sums, mins, maxs);
  k_stats<<<1, 128, 0, stream>>>(sums, mins, maxs, mu, tau, cnt, alpha);
  k_collect<<<PARTS * CH, 256, 0, stream>>>(x, mu, tau, cnt, cand, cap);
  k_select<<<CH, 256, (size_t)cap * 4, stream>>>(cand, cnt, mu, weight, bias,
                                                 sw, sb, cap, constv);
  k_affine<<<NBATCH * CH, 256, 0, stream>>>(x, sw, sb, out);
}

// Round 3
// 101.403 us; speedup vs baseline: 5.5330x; 5.5330x over previous
//
#include <hip/hip_runtime.h>
#include <cmath>

#ifndef M_PI
#define M_PI 3.14159265358979323846
#endif

static constexpr int CH     = 128;   // channels
static constexpr int NBATCH = 64;    // batch
static constexpr int HWSZ   = 3136;  // 56*56
static constexpr int HW4    = 784;   // HWSZ/4
static constexpr int PARTS  = 16;    // chunks per channel
static constexpr int SLPP   = NBATCH / PARTS;
static constexpr int KTOP   = 10;
static constexpr float EPSV = 1e-5f;
static constexpr int LBUF   = 4096;  // per-block LDS candidate buffer

// ---------------------------------------------------------------------------
// k_reduce: per (part, channel) block: sum / min / max (branchless)
// grid = PARTS*CH = 2048 blocks, 256 threads
// ---------------------------------------------------------------------------
__global__ __launch_bounds__(256) void k_reduce(const float* __restrict__ x,
                                                float* __restrict__ sums,
                                                float* __restrict__ mins,
                                                float* __restrict__ maxs) {
  const int bid  = blockIdx.x;
  const int c    = bid & (CH - 1);
  const int part = bid >> 7;
  const int tid  = threadIdx.x;
  const float4* x4 = reinterpret_cast<const float4*>(x);

  float s = 0.f, mn = 3.402823e38f, mx = -3.402823e38f;
  for (int sl = 0; sl < SLPP; ++sl) {
    const size_t base = (size_t)((part * SLPP + sl) * CH + c) * HW4;
    for (int i = tid; i < HW4; i += 256) {
      float4 v = x4[base + i];
      s += (v.x + v.y) + (v.z + v.w);
      mn = fminf(mn, fminf(fminf(v.x, v.y), fminf(v.z, v.w)));
      mx = fmaxf(mx, fmaxf(fmaxf(v.x, v.y), fmaxf(v.z, v.w)));
    }
  }
  for (int off = 32; off; off >>= 1) {
    s  += __shfl_down(s, off);
    mn  = fminf(mn, __shfl_down(mn, off));
    mx  = fmaxf(mx, __shfl_down(mx, off));
  }
  __shared__ float shs[4], shn[4], shx[4];
  const int lane = tid & 63, wid = tid >> 6;
  if (lane == 0) { shs[wid] = s; shn[wid] = mn; shx[wid] = mx; }
  __syncthreads();
  if (tid == 0) {
    sums[bid] = (shs[0] + shs[1]) + (shs[2] + shs[3]);
    mins[bid] = fminf(fminf(shn[0], shn[1]), fminf(shn[2], shn[3]));
    maxs[bid] = fmaxf(fmaxf(shx[0], shx[1]), fmaxf(shx[2], shx[3]));
  }
}

// ---------------------------------------------------------------------------
// k_stats: per channel mean + threshold; zero counters.  <<<1,128>>>
// ---------------------------------------------------------------------------
__global__ __launch_bounds__(128) void k_stats(const float* __restrict__ sums,
                                               const float* __restrict__ mins,
                                               const float* __restrict__ maxs,
                                               float* __restrict__ mu,
                                               float* __restrict__ tau,
                                               unsigned* __restrict__ cnt,
                                               float alpha) {
  const int c = threadIdx.x;
  float s = 0.f, mn = 3.402823e38f, mx = -3.402823e38f;
  #pragma unroll
  for (int p = 0; p < PARTS; ++p) {
    s += sums[p * CH + c];
    mn = fminf(mn, mins[p * CH + c]);
    mx = fmaxf(mx, maxs[p * CH + c]);
  }
  const float m = s * (1.0f / ((float)NBATCH * (float)HWSZ));
  mu[c]  = m;
  tau[c] = alpha * fmaxf(mx - m, m - mn);
  cnt[c] = 0u;
}

// ---------------------------------------------------------------------------
// k_collect: gather dev = |x - mu| >= tau into per-channel candidate buffer.
// LDS-buffered: per-element LDS atomics only; ONE global atomic per block.
// grid = PARTS*CH, 256 threads
// ---------------------------------------------------------------------------
__global__ __launch_bounds__(256) void k_collect(const float* __restrict__ x,
                                                 const float* __restrict__ mu,
                                                 const float* __restrict__ tau,
                                                 unsigned* __restrict__ cnt,
                                                 float* __restrict__ cand,
                                                 int cap) {
  __shared__ float buf[LBUF];
  __shared__ unsigned lcnt;
  __shared__ unsigned gbase;
  const int bid  = blockIdx.x;
  const int c    = bid & (CH - 1);
  const int part = bid >> 7;
  const int tid  = threadIdx.x;
  if (tid == 0) lcnt = 0u;
  __syncthreads();

  const float m = mu[c], t = tau[c];
  const float4* x4 = reinterpret_cast<const float4*>(x);

  for (int sl = 0; sl < SLPP; ++sl) {
    const size_t base = (size_t)((part * SLPP + sl) * CH + c) * HW4;
    for (int i = tid; i < HW4; i += 256) {
      float4 v = x4[base + i];
      float d0 = fabsf(v.x - m), d1 = fabsf(v.y - m);
      float d2 = fabsf(v.z - m), d3 = fabsf(v.w - m);
      if (d0 >= t) { unsigned p = atomicAdd(&lcnt, 1u); if (p < LBUF) buf[p] = d0; }
      if (d1 >= t) { unsigned p = atomicAdd(&lcnt, 1u); if (p < LBUF) buf[p] = d1; }
      if (d2 >= t) { unsigned p = atomicAdd(&lcnt, 1u); if (p < LBUF) buf[p] = d2; }
      if (d3 >= t) { unsigned p = atomicAdd(&lcnt, 1u); if (p < LBUF) buf[p] = d3; }
    }
  }
  __syncthreads();

  const unsigned n = min(lcnt, (unsigned)LBUF);
  if (tid == 0) gbase = atomicAdd(&cnt[c], n);
  __syncthreads();

  float* cc = cand + (size_t)c * cap;
  const unsigned gb = gbase;
  for (unsigned i = tid; i < n; i += 256) {
    unsigned p = gb + i;
    if (p < (unsigned)cap) cc[p] = buf[i];
  }
}

// ---------------------------------------------------------------------------
// k_select: exact top-10 of candidates -> (sw, sb).  <<<CH,256, cap*4>>>
// ---------------------------------------------------------------------------
__global__ __launch_bounds__(256) void k_select(const float* __restrict__ cand,
                                                const unsigned* __restrict__ cnt,
                                                const float* __restrict__ mu,
                                                const float* __restrict__ weight,
                                                const float* __restrict__ bias,
                                                float* __restrict__ sw,
                                                float* __restrict__ sb,
                                                int cap, float constv) {
  extern __shared__ float ls[];
  const int c   = blockIdx.x;
  const int tid = threadIdx.x;
  const int n   = (int)min(cnt[c], (unsigned)cap);
  const float* cc = cand + (size_t)c * cap;
  for (int i = tid; i < cap; i += 256) ls[i] = (i < n) ? cc[i] : -1.f;
  __syncthreads();

  __shared__ float swv[4];
  __shared__ int   swi[4];
  __shared__ float tot;
  if (tid == 0) tot = 0.f;
  const int lane = tid & 63, wid = tid >> 6;

  for (int it = 0; it < KTOP; ++it) {
    float best = -2.f; int bi = 0;
    for (int i = tid; i < cap; i += 256) {
      float v = ls[i];
      if (v > best) { best = v; bi = i; }
    }
    for (int off = 32; off; off >>= 1) {
      float ov = __shfl_down(best, off);
      int   oi = __shfl_down(bi, off);
      if (ov > best) { best = ov; bi = oi; }
    }
    if (lane == 0) { swv[wid] = best; swi[wid] = bi; }
    __syncthreads();
    if (tid == 0) {
      float bb = swv[0]; int bbi = swi[0];
      for (int w = 1; w < 4; ++w) if (swv[w] > bb) { bb = swv[w]; bbi = swi[w]; }
      tot += bb;
      ls[bbi] = -2.f;
    }
    __syncthreads();
  }

  if (tid == 0) {
    const float mtk = tot * (1.0f / KTOP) * constv;
    const float inv = 1.f / (mtk + EPSV);
    const float w   = inv * weight[c];
    sw[c] = w;
    sb[c] = bias[c] - mu[c] * w;
  }
}

// ---------------------------------------------------------------------------
// k_affine: out = fma(x, sw[c], sb[c]).  grid = NBATCH*CH, 256 threads
// ---------------------------------------------------------------------------
__global__ __launch_bounds__(256) void k_affine(const float* __restrict__ x,
                                                const float* __restrict__ sw,
                                                const float* __restrict__ sb,
                                                float* __restrict__ out) {
  const int s = blockIdx.x;           // n*CH + c
  const int c = s & (CH - 1);
  const float w = sw[c], b = sb[c];
  const float4* x4 = reinterpret_cast<const float4*>(x) + (size_t)s * HW4;
  float4*       o4 = reinterpret_cast<float4*>(out)     + (size_t)s * HW4;
  for (int i = threadIdx.x; i < HW4; i += 256) {
    float4 v = x4[i];
    float4 r;
    r.x = fmaf(v.x, w, b);
    r.y = fmaf(v.y, w, b);
    r.z = fmaf(v.z, w, b);
    r.w = fmaf(v.w, w, b);
    o4[i] = r;
  }
}

extern "C" void kernel_launch(void* const* d_in, const int* in_sizes, int n_in,
                              void* d_out, int out_size, void* d_ws, size_t ws_size,
                              hipStream_t stream) {
  const float* x      = (const float*)d_in[0];
  const float* weight = (const float*)d_in[1];
  const float* bias   = (const float*)d_in[2];
  float* out = (float*)d_out;
  float* ws  = (float*)d_ws;

  // ws layout (floats)
  float*    sums = ws;                 // 2048
  float*    mins = sums + PARTS * CH;  // 2048
  float*    maxs = mins + PARTS * CH;  // 2048
  float*    mu   = maxs + PARTS * CH;  // 128
  float*    tau  = mu + CH;            // 128
  float*    sw   = tau + CH;           // 128
  float*    sb   = sw + CH;            // 128
  unsigned* cnt  = (unsigned*)(sb + CH); // 128
  float*    cand = (float*)(cnt + CH);
  const size_t FIXED = (size_t)(cand - ws);

  // candidate capacity / threshold ladder based on available scratch
  const size_t avail = ws_size / 4;
  int cap; float alpha;
  if (avail >= FIXED + (size_t)CH * 8192) { cap = 8192; alpha = 0.55f; }
  else if (avail >= FIXED + (size_t)CH * 2048) { cap = 2048; alpha = 0.65f; }
  else { cap = 1024; alpha = 0.70f; }

  const double M = (double)NBATCH * (double)HWSZ;
  const float constv =
      (float)(0.5 * (1.0 + sqrt(M_PI * log(4.0))) / sqrt(2.0 * log(M)));

  k_reduce<<<PARTS * CH, 256, 0, stream>>>(x, sums, mins, maxs);
  k_stats<<<1, 128, 0, stream>>>(sums, mins, maxs, mu, tau, cnt, alpha);
  k_collect<<<PARTS * CH, 256, 0, stream>>>(x, mu, tau, cnt, cand, cap);
  k_select<<<CH, 256, (size_t)cap * 4, stream>>>(cand, cnt, mu, weight, bias,
                                                 sw, sb, cap, constv);
  k_affine<<<NBATCH * CH, 256, 0, stream>>>(x, sw, sb, out);
}